// Round 6
// baseline (191.957 us; speedup 1.0000x reference)
//
#include <hip/hip_runtime.h>

// DigiCaps dynamic routing — R25: W-tile pinned in LDS, b-loop per block.
// inputs [512,1152,8] f32, W [10,1152,16,8] f32, out v [512,10,16] f32.
// u_hat[b,j,i,d] = sum_k x[b,i,k] W[j,i,d,k]; logits via vsum recurrence;
// u_hat never materialized (3 recompute passes).
//
// Evidence trail:
//  R20/R21: spill artifacts (reg-prefetch; VGPR cap 64). Gate: VGPR~104-112,
//           FETCH <= ~25MB, else timing is void.
//  R18/R22/R23/R24: pass time 41-47us for EVERY decomposition (block count
//  x8 range, per-block work x8 range, LDS vs direct-global, barriers vs
//  none). Fixed global rate ~1 tile-unit/11us/CU; all pipes <25%; ~850GB/s
//  effective with MLP ~6 lines/CU -> READ-REQUEST LATENCY-BOUND. Constant
//  across all variants: per-unit read volume (W 20.6KB + x 8KB).
// R25: vary that constant. Block=(bg,ig) stages its W-tile ONCE (depends
// only on ig), then loops NLOOP_B=4 b-tiles: stage x (8KB) -> bar ->
// compute -> bar -> direct stores. Per-unit reads 28.6->13.4KB. Grid
// (2,144)=288. Unit codegen identical to R18; epilogue = R24 direct
// ushort4 stores (wl persists, no bounce possible; R24 shows ~neutral).
// part/squash/conv unchanged (144 slabs, proven).
// Carried: MFMA f32_16x16x32_bf16 (C: lane&15=b, (lane>>4)*4+reg=d);
// K=32 packs 4 i's; MODE1 masks B per q; fp16x2 logit butterfly; no
// max-subtract; bf16 pre-convert; (256,2) proven no-spill bounds.
// absmax prior 3.9e-3 (threshold 17.5e-3) — unit math identical.

#define NB 512
#define NI 1152
#define NJ 10
#define ND 16
#define NLOOP_B 4
#define NIGB 144   // i-groups of 8

typedef short          bf16x8 __attribute__((ext_vector_type(8)));
typedef unsigned short u16x8  __attribute__((ext_vector_type(8)));
typedef float          f32x4  __attribute__((ext_vector_type(4)));
typedef __fp16         h16x2  __attribute__((ext_vector_type(2)));

constexpr float EPS_ = 1e-7f;

constexpr size_t XB_ELEMS = (size_t)NB * NI * 8;       // bf16
constexpr size_t WB_ELEMS = (size_t)NJ * NI * ND * 8;  // bf16
constexpr int    XQ = 1179648;                         // x float4 quads
constexpr int    WQ = 368640;                          // W float4 quads

__device__ inline unsigned short f2bf(float f) {   // RNE f32->bf16
    unsigned u = __float_as_uint(f);
    return (unsigned short)((u + 0x7fffu + ((u >> 16) & 1u)) >> 16);
}
__device__ inline float bf2f(unsigned short u) {
    return __uint_as_float((unsigned)u << 16);
}

__global__ __launch_bounds__(256)
void conv_bf16(const float* __restrict__ x, const float* __restrict__ Wg,
               unsigned short* __restrict__ xb, unsigned short* __restrict__ wb)
{
    int t = blockIdx.x * 256 + threadIdx.x;
    if (t < XQ) {
        float4 v = ((const float4*)x)[t];
        ushort4 o; o.x=f2bf(v.x); o.y=f2bf(v.y); o.z=f2bf(v.z); o.w=f2bf(v.w);
        ((ushort4*)xb)[t] = o;
    } else if (t - XQ < WQ) {
        int u = t - XQ;
        float4 v = ((const float4*)Wg)[u];
        ushort4 o; o.x=f2bf(v.x); o.y=f2bf(v.y); o.z=f2bf(v.z); o.w=f2bf(v.w);
        ((ushort4*)wb)[u] = o;
    }
}

// Block: W-tile (8 i, all j,d) pinned in LDS; loop NLOOP_B b-tiles of 64
// (4 waves x 16 b). LDS: wl 20608 B + xl 9216 B = 29824 B.
template <int MODE>
__global__ __launch_bounds__(256, 2)
void caps_pass(const unsigned short* __restrict__ xb,
               const unsigned short* __restrict__ wb,
               const float* __restrict__ vsum_g,
               unsigned short* __restrict__ part)
{
    // wl: granule g = il*161 + j*16 + d (161-pad breaks kg-group aliasing,
    // proven). xl: row stride 9 granules (8 il + pad).
    __shared__ __align__(16) char smem[29824];
    unsigned short* wl = (unsigned short*)smem;                 // 1288 granules
    unsigned short* xl = (unsigned short*)(smem + 20608);       // 576 granules

    const int tid = threadIdx.x, lane = tid & 63, w = tid >> 6;
    const int bl = lane & 15, kg = lane >> 4;
    const int bg = blockIdx.x, ig = blockIdx.y;
    const int i0 = ig * 8;
    const int brow = w * 16 + bl;

    // stage W ONCE: 1280 real granules -> slot il*161 + rem
#pragma unroll
    for (int r = 0; r < 5; ++r) {
        int g  = tid + r * 256;
        int il = g / 160, rem = g - il * 160;
        const unsigned short* src =
            wb + ((size_t)(rem >> 4) * NI + (i0 + il)) * 128 + (rem & 15) * 8;
        *(u16x8*)(wl + (il * 161 + rem) * 8) = *(const u16x8*)src;
    }

    const f32x4  zero  = {0.f, 0.f, 0.f, 0.f};
    const bf16x8 zerob = {0, 0, 0, 0, 0, 0, 0, 0};

#pragma unroll 1
    for (int u = 0; u < NLOOP_B; ++u) {
        const int b0 = (bg * NLOOP_B + u) * 64;
        const int b  = b0 + w * 16 + bl;

        // stage x for this b-tile: slot brr*9 + il <- x[b0+brr, i0+il, 0:8]
#pragma unroll
        for (int r = 0; r < 2; ++r) {
            int g = tid + r * 256;
            int brr = g >> 3, il = g & 7;
            *(u16x8*)(xl + (brr * 9 + il) * 8) =
                *(const u16x8*)(xb + ((size_t)(b0 + brr) * NI + i0 + il) * 8);
        }

        f32x4 vs[NJ];
        if (MODE == 1) {
#pragma unroll
            for (int j = 0; j < NJ; ++j)
                vs[j] = *(const f32x4*)(vsum_g + (size_t)b * 160 + j * 16 + kg * 4);
        }

        __syncthreads();   // W (first trip) + this tile's x visible

        f32x4 sacc[NJ];
#pragma unroll
        for (int j = 0; j < NJ; ++j) sacc[j] = zero;

#pragma unroll
        for (int t4 = 0; t4 < 2; ++t4) {
            // A-frags: lane (kg,bl) = W[i0+t4*4+kg, j, d=bl, 0:8] — K=32
            // packed, all 64 lanes real; 10 reads per FOUR i's.
            bf16x8 afull[NJ];
#pragma unroll
            for (int j = 0; j < NJ; ++j)
                afull[j] = *(const bf16x8*)(wl + (((t4 * 4 + kg) * 161) + j * 16 + bl) * 8);
            bf16x8 xv = *(const bf16x8*)(xl + (brow * 9 + t4 * 4 + kg) * 8);

            if (MODE == 0) {
#pragma unroll
                for (int j = 0; j < NJ; ++j)
                    sacc[j] = __builtin_amdgcn_mfma_f32_16x16x32_bf16(afull[j], xv, sacc[j], 0, 0, 0);
            } else {
#pragma unroll
                for (int q = 0; q < 4; ++q) {
                    const bf16x8 bq = (kg == q) ? xv : zerob;   // isolate i
                    f32x4 uh[NJ];
#pragma unroll
                    for (int j = 0; j < NJ; ++j)
                        uh[j] = __builtin_amdgcn_mfma_f32_16x16x32_bf16(afull[j], bq, zero, 0, 0, 0);

                    // per-lane partial dots over this lane's 4 d's (f32)
                    float bd[NJ];
#pragma unroll
                    for (int j = 0; j < NJ; ++j)
                        bd[j] = uh[j][0] * vs[j][0] + uh[j][1] * vs[j][1]
                              + uh[j][2] * vs[j][2] + uh[j][3] * vs[j][3];

                    // fp16x2-packed butterfly over the 4 d-quad lane groups:
                    // 10 shfl + 10 pk_add.
                    h16x2 pk[5];
#pragma unroll
                    for (int jp = 0; jp < 5; ++jp)
                        pk[jp] = __builtin_amdgcn_cvt_pkrtz(bd[2 * jp], bd[2 * jp + 1]);
#pragma unroll
                    for (int jp = 0; jp < 5; ++jp) {
                        float f = __shfl_xor(__builtin_bit_cast(float, pk[jp]), 16, 64);
                        pk[jp] = pk[jp] + __builtin_bit_cast(h16x2, f);
                    }
#pragma unroll
                    for (int jp = 0; jp < 5; ++jp) {
                        float f = __shfl_xor(__builtin_bit_cast(float, pk[jp]), 32, 64);
                        pk[jp] = pk[jp] + __builtin_bit_cast(h16x2, f);
                    }

                    // softmax over j, no max-subtract (|logit| <= ~3)
                    float e[NJ];
#pragma unroll
                    for (int jp = 0; jp < 5; ++jp) {
                        e[2 * jp]     = __expf((float)pk[jp][0]);
                        e[2 * jp + 1] = __expf((float)pk[jp][1]);
                    }
                    float Z = ((e[0] + e[1]) + (e[2] + e[3]))
                            + ((e[4] + e[5]) + (e[6] + e[7])) + (e[8] + e[9]);
                    const float rZ = 1.f / Z;
#pragma unroll
                    for (int j = 0; j < NJ; ++j) {
                        const float c = e[j] * rZ;
                        sacc[j] += c * uh[j];
                    }
                }
            }
        }

        __syncthreads();   // all lanes done reading xl before next overwrite

        // epilogue per b-tile: direct bf16 stores (wl persists; no bounce).
        // Per j the wave writes 16 rows x 32B; j-unroll covers each 64B
        // line back-to-back (L2 write-merge) — R24-verified neutral.
        unsigned short* pp = part + ((size_t)ig * NB + b) * 160;
#pragma unroll
        for (int j = 0; j < NJ; ++j) {
            ushort4 o;
            o.x = f2bf(sacc[j][0]); o.y = f2bf(sacc[j][1]);
            o.z = f2bf(sacc[j][2]); o.w = f2bf(sacc[j][3]);
            *(ushort4*)(pp + j * 16 + kg * 4) = o;
        }
    }
}

// Sum 144 bf16 ig-partials, scale, squash over d (16-lane shfl), update vsum/out.
__global__ __launch_bounds__(256)
void squash_reduce(const unsigned short* __restrict__ part,
                   float* __restrict__ vsum_g, float* __restrict__ out,
                   float alpha, int mode)
{
    const int t = blockIdx.x * 256 + threadIdx.x;   // < 81920 = b*160 + j*16 + d
    const unsigned short* p = part + t;
    float a0 = 0.f, a1 = 0.f, a2 = 0.f, a3 = 0.f;
#pragma unroll 4
    for (int ig = 0; ig < NIGB; ig += 4) {
        a0 += bf2f(p[(size_t)ig * 81920]);
        a1 += bf2f(p[(size_t)(ig + 1) * 81920]);
        a2 += bf2f(p[(size_t)(ig + 2) * 81920]);
        a3 += bf2f(p[(size_t)(ig + 3) * 81920]);
    }
    const float s = ((a0 + a1) + (a2 + a3)) * alpha;

    float sq = s * s;
    sq += __shfl_xor(sq, 1, 64);
    sq += __shfl_xor(sq, 2, 64);
    sq += __shfl_xor(sq, 4, 64);
    sq += __shfl_xor(sq, 8, 64);
    const float sc = sq / ((1.f + sq) * sqrtf(sq + EPS_));
    const float v  = sc * s;

    if (mode == 0)      vsum_g[t] = v;
    else if (mode == 1) vsum_g[t] += v;
    else                out[t] = v;
}

extern "C" void kernel_launch(void* const* d_in, const int* in_sizes, int n_in,
                              void* d_out, int out_size, void* d_ws, size_t ws_size,
                              hipStream_t stream)
{
    const float* inp = (const float*)d_in[0];
    const float* Wg  = (const float*)d_in[1];
    float* out = (float*)d_out;

    unsigned short* xbp  = (unsigned short*)d_ws;
    unsigned short* wbp  = xbp + XB_ELEMS;
    unsigned short* part = wbp + WB_ELEMS;                    // [144][512][160] bf16
    float* vsum = (float*)(part + (size_t)NIGB * NB * 160);   // [512][10][16] f32

    conv_bf16<<<(XQ + WQ + 255) / 256, 256, 0, stream>>>(inp, Wg, xbp, wbp);

    dim3 grid(8 / NLOOP_B, NIGB);   // (2,144) = 288 blocks; W staged once/block
    // iter 0: c uniform 1/10 (folded into alpha); K=32 contracts 4 i's exactly
    caps_pass<0><<<grid, 256, 0, stream>>>(xbp, wbp, nullptr, part);
    squash_reduce<<<320, 256, 0, stream>>>(part, vsum, out, 0.1f, 0);
    // iter 1: logits = u_hat . v0
    caps_pass<1><<<grid, 256, 0, stream>>>(xbp, wbp, vsum, part);
    squash_reduce<<<320, 256, 0, stream>>>(part, vsum, out, 1.0f, 1);
    // iter 2: logits = u_hat . (v0+v1)
    caps_pass<1><<<grid, 256, 0, stream>>>(xbp, wbp, vsum, part);
    squash_reduce<<<320, 256, 0, stream>>>(part, vsum, out, 1.0f, 2);
}

// Round 8
// 156.989 us; speedup vs baseline: 1.2227x; 1.2227x over previous
//
#include <hip/hip_runtime.h>

// DigiCaps dynamic routing — R26 (resubmit; prior bench = container infra
// failure, kernel untested): R24 substrate + __launch_bounds__(256,1).
// inputs [512,1152,8] f32, W [10,1152,16,8] f32, out v [512,10,16] f32.
// u_hat[b,j,i,d] = sum_k x[b,i,k] W[j,i,d,k]; logits via vsum recurrence;
// u_hat never materialized (3 recompute passes).
//
// Evidence trail (19 structural variants, caps 41-47us ALWAYS):
//  R20/R21: spill artifacts (reg-prefetch at 128-cap; (512,4) VGPR cap 64).
//  R18/R22/R23/R24: insensitive to block count (288-2304), per-block work
//    (0.5x-4x), LDS vs direct-global, barriers vs none.
//  R25: FETCH halved (16.4->8.2MB, W pinned) -> time UNCHANGED 45.3us.
//    Occupancy 8.5% at 288 blocks -> per-block busy ~27us -> per-unit
//    ~7-11us latency is REAL (wave-level), ~80 cy/instruction exposed.
// Diagnosis: at ~1.4 waves/SIMD every LDS/shfl (~120cy) and load
// (~200-900cy) in the chain is exposed; at the (256,2)=128-VGPR cap the
// compiler CANNOT keep the 8 unrolled q-chains / 20+ independent loads in
// flight -> serializes to fit 104 regs. Prior session proved minimums >2
// spill; it never RELAXED the bound.
// R26: (256,1) -> 256-VGPR budget. Substrate = R24 (no LDS, no barriers:
// all loads & chains visible to scheduler, nothing pins order). Static occ
// at ~200 VGPR ~= 2 waves/SIMD >= observed 1.4 -> nothing lost.
// Spill gate: VGPR <= 256 AND FETCH <= ~25MB, else timing void.
// Carried: MFMA f32_16x16x32_bf16 (C: lane&15=b, (lane>>4)*4+reg=d);
// K=32 packs 4 i's (all lanes real); MODE1 masks B per q; fp16x2 logit
// butterfly; no max-subtract; bf16 pre-convert; part 144 slabs + proven
// squash_reduce. absmax prior 3.9e-3 (threshold 17.5e-3).

#define NB 512
#define NI 1152
#define NJ 10
#define ND 16
#define NIGB 144   // i-groups of 8

typedef short          bf16x8 __attribute__((ext_vector_type(8)));
typedef unsigned short u16x8  __attribute__((ext_vector_type(8)));
typedef float          f32x4  __attribute__((ext_vector_type(4)));
typedef __fp16         h16x2  __attribute__((ext_vector_type(2)));

constexpr float EPS_ = 1e-7f;

constexpr size_t XB_ELEMS = (size_t)NB * NI * 8;       // bf16
constexpr size_t WB_ELEMS = (size_t)NJ * NI * ND * 8;  // bf16
constexpr int    XQ = 1179648;                         // x float4 quads
constexpr int    WQ = 368640;                          // W float4 quads

__device__ inline unsigned short f2bf(float f) {   // RNE f32->bf16
    unsigned u = __float_as_uint(f);
    return (unsigned short)((u + 0x7fffu + ((u >> 16) & 1u)) >> 16);
}
__device__ inline float bf2f(unsigned short u) {
    return __uint_as_float((unsigned)u << 16);
}

__global__ __launch_bounds__(256)
void conv_bf16(const float* __restrict__ x, const float* __restrict__ Wg,
               unsigned short* __restrict__ xb, unsigned short* __restrict__ wb)
{
    int t = blockIdx.x * 256 + threadIdx.x;
    if (t < XQ) {
        float4 v = ((const float4*)x)[t];
        ushort4 o; o.x=f2bf(v.x); o.y=f2bf(v.y); o.z=f2bf(v.z); o.w=f2bf(v.w);
        ((ushort4*)xb)[t] = o;
    } else if (t - XQ < WQ) {
        int u = t - XQ;
        float4 v = ((const float4*)Wg)[u];
        ushort4 o; o.x=f2bf(v.x); o.y=f2bf(v.y); o.z=f2bf(v.z); o.w=f2bf(v.w);
        ((ushort4*)wb)[u] = o;
    }
}

// Block: 4 independent waves; each wave owns 16 b x 8 i. No LDS, no
// barriers. (256,1): 256-VGPR budget so the scheduler can hoist loads and
// interleave the 8 q-softmax chains.
// wb layout [j][i][d][k]: granule (16B) addr = ((j*NI + i)*16 + d) * 8 shorts.
template <int MODE>
__global__ __launch_bounds__(256, 1)
void caps_pass(const unsigned short* __restrict__ xb,
               const unsigned short* __restrict__ wb,
               const float* __restrict__ vsum_g,
               unsigned short* __restrict__ part)
{
    const int tid = threadIdx.x, lane = tid & 63, w = tid >> 6;
    const int bl = lane & 15, kg = lane >> 4;
    const int bg = blockIdx.x, ig = blockIdx.y;
    const int i0 = ig * 8, b0 = bg * 64;
    const int b  = b0 + w * 16 + bl;

    f32x4 vs[NJ];
    if (MODE == 1) {
#pragma unroll
        for (int j = 0; j < NJ; ++j)
            vs[j] = *(const f32x4*)(vsum_g + (size_t)b * 160 + j * 16 + kg * 4);
    }

    const f32x4  zero  = {0.f, 0.f, 0.f, 0.f};
    const bf16x8 zerob = {0, 0, 0, 0, 0, 0, 0, 0};
    f32x4 sacc[NJ];
#pragma unroll
    for (int j = 0; j < NJ; ++j) sacc[j] = zero;

#pragma unroll
    for (int t4 = 0; t4 < 2; ++t4) {
        const int il = i0 + t4 * 4 + kg;   // this lane's input capsule
        // A-frags direct from global (L2-resident W): per j, the wave's 64
        // lanes cover W[j, i0+t4*4 .. +3, 0:16, 0:8] = contiguous 1KB.
        const unsigned short* wbase = wb + (size_t)il * 128 + bl * 8;
        bf16x8 afull[NJ];
#pragma unroll
        for (int j = 0; j < NJ; ++j)
            afull[j] = *(const bf16x8*)(wbase + (size_t)j * (NI * 128));
        // B-frag: x[b, il, 0:8] — per (w,kg) quad the wave reads 16 64B lines.
        bf16x8 xv = *(const bf16x8*)(xb + ((size_t)b * NI + il) * 8);

        if (MODE == 0) {
#pragma unroll
            for (int j = 0; j < NJ; ++j)
                sacc[j] = __builtin_amdgcn_mfma_f32_16x16x32_bf16(afull[j], xv, sacc[j], 0, 0, 0);
        } else {
#pragma unroll
            for (int q = 0; q < 4; ++q) {
                const bf16x8 bq = (kg == q) ? xv : zerob;   // isolate i = i0+t4*4+q
                f32x4 uh[NJ];
#pragma unroll
                for (int j = 0; j < NJ; ++j)
                    uh[j] = __builtin_amdgcn_mfma_f32_16x16x32_bf16(afull[j], bq, zero, 0, 0, 0);

                // per-lane partial dots over this lane's 4 d's (f32)
                float bd[NJ];
#pragma unroll
                for (int j = 0; j < NJ; ++j)
                    bd[j] = uh[j][0] * vs[j][0] + uh[j][1] * vs[j][1]
                          + uh[j][2] * vs[j][2] + uh[j][3] * vs[j][3];

                // fp16x2-packed butterfly over the 4 d-quad lane groups:
                // 10 shfl + 10 pk_add.
                h16x2 pk[5];
#pragma unroll
                for (int jp = 0; jp < 5; ++jp)
                    pk[jp] = __builtin_amdgcn_cvt_pkrtz(bd[2 * jp], bd[2 * jp + 1]);
#pragma unroll
                for (int jp = 0; jp < 5; ++jp) {
                    float f = __shfl_xor(__builtin_bit_cast(float, pk[jp]), 16, 64);
                    pk[jp] = pk[jp] + __builtin_bit_cast(h16x2, f);
                }
#pragma unroll
                for (int jp = 0; jp < 5; ++jp) {
                    float f = __shfl_xor(__builtin_bit_cast(float, pk[jp]), 32, 64);
                    pk[jp] = pk[jp] + __builtin_bit_cast(h16x2, f);
                }

                // softmax over j, no max-subtract (|logit| <= ~3, exp safe)
                float e[NJ];
#pragma unroll
                for (int jp = 0; jp < 5; ++jp) {
                    e[2 * jp]     = __expf((float)pk[jp][0]);
                    e[2 * jp + 1] = __expf((float)pk[jp][1]);
                }
                float Z = ((e[0] + e[1]) + (e[2] + e[3]))
                        + ((e[4] + e[5]) + (e[6] + e[7])) + (e[8] + e[9]);
                const float rZ = 1.f / Z;
#pragma unroll
                for (int j = 0; j < NJ; ++j) {
                    const float c = e[j] * rZ;
                    sacc[j] += c * uh[j];
                }
            }
        }
    }

    // epilogue: direct bf16 stores; lane (kg,bl) owns part[ig][b][j*16+kg*4..+4].
    // Per store-instr the wave covers 16 rows x 32B contiguous; the j-unroll
    // fully covers each 64B line back-to-back (L2 write-merge).
    unsigned short* pp = part + ((size_t)ig * NB + b) * 160;
#pragma unroll
    for (int j = 0; j < NJ; ++j) {
        ushort4 o;
        o.x = f2bf(sacc[j][0]); o.y = f2bf(sacc[j][1]);
        o.z = f2bf(sacc[j][2]); o.w = f2bf(sacc[j][3]);
        *(ushort4*)(pp + j * 16 + kg * 4) = o;
    }
}

// Sum 144 bf16 ig-partials, scale, squash over d (16-lane shfl), update vsum/out.
__global__ __launch_bounds__(256)
void squash_reduce(const unsigned short* __restrict__ part,
                   float* __restrict__ vsum_g, float* __restrict__ out,
                   float alpha, int mode)
{
    const int t = blockIdx.x * 256 + threadIdx.x;   // < 81920 = b*160 + j*16 + d
    const unsigned short* p = part + t;
    float a0 = 0.f, a1 = 0.f, a2 = 0.f, a3 = 0.f;
#pragma unroll 4
    for (int ig = 0; ig < NIGB; ig += 4) {
        a0 += bf2f(p[(size_t)ig * 81920]);
        a1 += bf2f(p[(size_t)(ig + 1) * 81920]);
        a2 += bf2f(p[(size_t)(ig + 2) * 81920]);
        a3 += bf2f(p[(size_t)(ig + 3) * 81920]);
    }
    const float s = ((a0 + a1) + (a2 + a3)) * alpha;

    float sq = s * s;
    sq += __shfl_xor(sq, 1, 64);
    sq += __shfl_xor(sq, 2, 64);
    sq += __shfl_xor(sq, 4, 64);
    sq += __shfl_xor(sq, 8, 64);
    const float sc = sq / ((1.f + sq) * sqrtf(sq + EPS_));
    const float v  = sc * s;

    if (mode == 0)      vsum_g[t] = v;
    else if (mode == 1) vsum_g[t] += v;
    else                out[t] = v;
}

extern "C" void kernel_launch(void* const* d_in, const int* in_sizes, int n_in,
                              void* d_out, int out_size, void* d_ws, size_t ws_size,
                              hipStream_t stream)
{
    const float* inp = (const float*)d_in[0];
    const float* Wg  = (const float*)d_in[1];
    float* out = (float*)d_out;

    unsigned short* xbp  = (unsigned short*)d_ws;
    unsigned short* wbp  = xbp + XB_ELEMS;
    unsigned short* part = wbp + WB_ELEMS;                    // [144][512][160] bf16
    float* vsum = (float*)(part + (size_t)NIGB * NB * 160);   // [512][10][16] f32

    conv_bf16<<<(XQ + WQ + 255) / 256, 256, 0, stream>>>(inp, Wg, xbp, wbp);

    dim3 grid(8, NIGB);   // (8,144) = 1152 blocks — R18/R24 A/B baseline
    // iter 0: c uniform 1/10 (folded into alpha); K=32 contracts 4 i's exactly
    caps_pass<0><<<grid, 256, 0, stream>>>(xbp, wbp, nullptr, part);
    squash_reduce<<<320, 256, 0, stream>>>(part, vsum, out, 0.1f, 0);
    // iter 1: logits = u_hat . v0
    caps_pass<1><<<grid, 256, 0, stream>>>(xbp, wbp, vsum, part);
    squash_reduce<<<320, 256, 0, stream>>>(part, vsum, out, 1.0f, 1);
    // iter 2: logits = u_hat . (v0+v1)
    caps_pass<1><<<grid, 256, 0, stream>>>(xbp, wbp, vsum, part);
    squash_reduce<<<320, 256, 0, stream>>>(part, vsum, out, 1.0f, 2);
}